// Round 10
// baseline (804.610 us; speedup 1.0000x reference)
//
#include <hip/hip_runtime.h>
#include <math.h>

#define HD 32      // hidden dim
#define FIN 64     // input features
#define NL 3       // num BernConv layers
#define NC 2       // num classes

#define TILE 4096  // edges per partition tile
#define CAP  3072  // max edges per bucket (mean ~2046, 12 sigma margin)
#define BMAX 1024  // max buckets (N <= 131072 with 128 nodes/bucket)

typedef __attribute__((ext_vector_type(8))) short bf16x8;
typedef __attribute__((ext_vector_type(4))) float f32x4;

// fast tanh; |rel err| ~1e-7, threshold 7e-2
__device__ __forceinline__ float fast_tanh(float x) {
    float e = __expf(2.0f * x);
    return 1.0f - 2.0f * __builtin_amdgcn_rcpf(e + 1.0f);
}

// fp32 -> bf16 bits with round-to-nearest-even (values are finite here)
__device__ __forceinline__ unsigned int f2bf(float f) {
    unsigned int u = __float_as_uint(f);
    return (u + 0x7fffu + ((u >> 16) & 1u)) >> 16;
}
__device__ __forceinline__ unsigned int pack2(float lo, float hi) {
    return f2bf(lo) | (f2bf(hi) << 16);
}
// bf16 pair -> fp32 (exact, just bit shifts)
__device__ __forceinline__ float bflo(unsigned int u) { return __uint_as_float(u << 16); }
__device__ __forceinline__ float bfhi(unsigned int u) { return __uint_as_float(u & 0xffff0000u); }

// split x into bf16 hi + bf16 lo (residual); hi+lo recovers x to ~2^-17 rel
__device__ __forceinline__ void pack_hilo(const float* v, bf16x8& hi, bf16x8& lo) {
#pragma unroll
    for (int e = 0; e < 8; ++e) {
        unsigned int uh = f2bf(v[e]);
        float xh = __uint_as_float(uh << 16);
        unsigned int ul = f2bf(v[e] - xh);
        hi[e] = (short)uh;
        lo[e] = (short)ul;
    }
}

// ---------------- gcursor init ----------------
__global__ __launch_bounds__(256) void init_kernel(int* __restrict__ gcursor, int B) {
    int b = blockIdx.x * 256 + threadIdx.x;
    if (b < B) gcursor[b] = b * CAP;
}

// ---------------- LDS-staged partition: bucket edges by dst>>7 ----------------
// bucket_buf keeps the PACKED (src<<7 | dstLow) form — the edge-parallel
// gathers decode it directly (no CSR build / bucket_buf rewrite anymore).
__global__ __launch_bounds__(256) void partition_kernel(const int* __restrict__ src,
                                                        const int* __restrict__ dst,
                                                        int* __restrict__ gcursor,
                                                        unsigned int* __restrict__ bucket_buf,
                                                        int E) {
    __shared__ unsigned int vals[TILE];
    __shared__ unsigned short bid[TILE];
    __shared__ int hist[BMAX];
    __shared__ int lcur[BMAX];
    __shared__ int goff[BMAX];
    __shared__ int sc[256];
    int t = threadIdx.x;
    int tile_base = blockIdx.x * TILE;
    int n_tile = min(TILE, E - tile_base);

    for (int i = t; i < BMAX; i += 256) hist[i] = 0;
    __syncthreads();

    unsigned int pk[TILE / 256];
    int bk[TILE / 256];
#pragma unroll
    for (int k = 0; k < TILE / 256; ++k) {
        int e = tile_base + k * 256 + t;
        if (e < E) {
            int s = src[e], d = dst[e];
            int b = d >> 7;
            pk[k] = ((unsigned)s << 7) | (unsigned)(d & 127);
            bk[k] = b;
            atomicAdd(&hist[b], 1);
        } else bk[k] = -1;
    }
    __syncthreads();

    int base4 = t * 4;
    int sum4 = hist[base4] + hist[base4 + 1] + hist[base4 + 2] + hist[base4 + 3];
    sc[t] = sum4;
    __syncthreads();
    for (int off = 1; off < 256; off <<= 1) {
        int v = (t >= off) ? sc[t - off] : 0;
        __syncthreads();
        sc[t] += v;
        __syncthreads();
    }
    int run = sc[t] - sum4;
#pragma unroll
    for (int j = 0; j < 4; ++j) {
        int tmp = hist[base4 + j];
        hist[base4 + j] = run;
        lcur[base4 + j] = run;
        run += tmp;
    }
    __syncthreads();

#pragma unroll
    for (int k = 0; k < TILE / 256; ++k) {
        if (bk[k] >= 0) {
            int pos = atomicAdd(&lcur[bk[k]], 1);
            vals[pos] = pk[k];
            bid[pos] = (unsigned short)bk[k];
        }
    }
    __syncthreads();

    for (int b = t; b < BMAX; b += 256) {
        int cnt = lcur[b] - hist[b];
        goff[b] = (cnt > 0) ? atomicAdd(&gcursor[b], cnt) : 0;
    }
    __syncthreads();

    for (int i = t; i < n_tile; i += 256) {
        int b = bid[i];
        int addr = goff[b] + (i - hist[b]);
        if (addr < (b + 1) * CAP)
            bucket_buf[addr] = vals[i];
    }
}

// ---------------- per-bucket degree histogram -> dinv (CSR build eliminated) ----------------
__global__ __launch_bounds__(256) void deg_kernel(const unsigned int* __restrict__ bucket_buf,
                                                  const int* __restrict__ gcursor,
                                                  float* __restrict__ dinv, int N) {
    __shared__ int ldeg[128];
    int b = blockIdx.x;
    int t = threadIdx.x;
    int base = b * CAP;
    int cnt = min(gcursor[b] - base, CAP);
    if (t < 128) ldeg[t] = 0;
    __syncthreads();
    for (int i = t; i < cnt; i += 256)
        atomicAdd(&ldeg[bucket_buf[base + i] & 127], 1);
    __syncthreads();
    if (t < 128) {
        int node = (b << 7) + t;
        if (node < N) dinv[node] = rsqrtf(fmaxf((float)ldeg[t], 1.0f));
    }
}

// ---------------- MLP in via MFMA: h = relu(feat@W1+b1)@W2+b2 ----------------
__global__ __launch_bounds__(256) void mlp_kernel(const float* __restrict__ feat,
                                                  const float* __restrict__ W1,
                                                  const float* __restrict__ b1,
                                                  const float* __restrict__ W2,
                                                  const float* __restrict__ b2,
                                                  const float* __restrict__ dinv,
                                                  float* __restrict__ hout,
                                                  uint4* __restrict__ hs_b, int N) {
    __shared__ unsigned short w1t[32][72];      // W1^T [j][k], pad 64->72
    __shared__ unsigned short w2t[32][40];      // W2^T [j][k], pad 32->40
    __shared__ unsigned short h1t[4][16][40];   // per-wave relu(h1) [row][j] bf16
    __shared__ unsigned short h2t[4][16][40];   // per-wave dinv*h2   [row][j] bf16

    int lt = threadIdx.x;
    for (int i = lt; i < FIN * HD; i += 256) {
        int k = i >> 5, j = i & 31;
        w1t[j][k] = (unsigned short)f2bf(W1[i]);
    }
    for (int i = lt; i < HD * HD; i += 256) {
        int k = i >> 5, j = i & 31;
        w2t[j][k] = (unsigned short)f2bf(W2[i]);
    }
    __syncthreads();

    int w = lt >> 6;
    int l = lt & 63;
    int g = l >> 4;
    int c = l & 15;
    int base = blockIdx.x * 64 + w * 16;

    int row = base + c;
    int rowc = (row < N) ? row : (N - 1);
    const float* fr = feat + (size_t)rowc * FIN;
    bf16x8 a1[2];
#pragma unroll
    for (int ks = 0; ks < 2; ++ks) {
        const float4* p = (const float4*)(fr + ks * 32 + 8 * g);
        float4 u0 = p[0], u1 = p[1];
        bf16x8 a;
        a[0] = (short)f2bf(u0.x); a[1] = (short)f2bf(u0.y);
        a[2] = (short)f2bf(u0.z); a[3] = (short)f2bf(u0.w);
        a[4] = (short)f2bf(u1.x); a[5] = (short)f2bf(u1.y);
        a[6] = (short)f2bf(u1.z); a[7] = (short)f2bf(u1.w);
        a1[ks] = a;
    }

    f32x4 acc[2];
#pragma unroll
    for (int nt = 0; nt < 2; ++nt) { acc[nt][0] = 0.f; acc[nt][1] = 0.f; acc[nt][2] = 0.f; acc[nt][3] = 0.f; }
#pragma unroll
    for (int nt = 0; nt < 2; ++nt) {
#pragma unroll
        for (int ks = 0; ks < 2; ++ks) {
            bf16x8 b = *(const bf16x8*)&w1t[nt * 16 + c][ks * 32 + 8 * g];
            acc[nt] = __builtin_amdgcn_mfma_f32_16x16x32_bf16(a1[ks], b, acc[nt], 0, 0, 0);
        }
    }

    float b1v0 = b1[c], b1v1 = b1[16 + c];
#pragma unroll
    for (int r = 0; r < 4; ++r) {
        h1t[w][4 * g + r][c]      = (unsigned short)f2bf(fmaxf(acc[0][r] + b1v0, 0.0f));
        h1t[w][4 * g + r][16 + c] = (unsigned short)f2bf(fmaxf(acc[1][r] + b1v1, 0.0f));
    }
    __syncthreads();

    bf16x8 a2 = *(const bf16x8*)&h1t[w][c][8 * g];
    f32x4 acc2[2];
#pragma unroll
    for (int nt = 0; nt < 2; ++nt) { acc2[nt][0] = 0.f; acc2[nt][1] = 0.f; acc2[nt][2] = 0.f; acc2[nt][3] = 0.f; }
#pragma unroll
    for (int nt = 0; nt < 2; ++nt) {
        bf16x8 b = *(const bf16x8*)&w2t[nt * 16 + c][8 * g];
        acc2[nt] = __builtin_amdgcn_mfma_f32_16x16x32_bf16(a2, b, acc2[nt], 0, 0, 0);
    }

    float b2v0 = b2[c], b2v1 = b2[16 + c];
#pragma unroll
    for (int r = 0; r < 4; ++r) {
        int rr = base + 4 * g + r;
        int rc = (rr < N) ? rr : (N - 1);
        float dv = dinv[rc];
        float v0 = acc2[0][r] + b2v0;
        float v1 = acc2[1][r] + b2v1;
        if (rr < N) {
            hout[(size_t)rr * HD + c]      = v0;
            hout[(size_t)rr * HD + 16 + c] = v1;
        }
        h2t[w][4 * g + r][c]      = (unsigned short)f2bf(dv * v0);
        h2t[w][4 * g + r][16 + c] = (unsigned short)f2bf(dv * v1);
    }
    __syncthreads();

    int nrow = base + c;
    if (nrow < N) {
        uint4 u = *(const uint4*)&h2t[w][c][8 * g];
        hs_b[(size_t)nrow * 4 + g] = u;
    }
}

// ---------------- gather #1, edge-parallel per bucket ----------------
// Block = bucket (128 consecutive dst nodes). 4 lanes/edge decode packed
// (src<<7|dstLow); quad-merged 64B table read; accumulate via LDS float
// atomics into accum[dstLow][36] (random dstLow ~ 2-way bank alias = free).
// NO degree divergence (work = cnt, balanced), no serial per-node chain,
// no CSR. Epilogue (s0, f1s_b writes + h reads) is fully coalesced since
// the bucket's nodes are consecutive.
__global__ __launch_bounds__(256) void gather1_kernel(const float* __restrict__ h,
                                                      const uint4* __restrict__ hs_b,
                                                      const float* __restrict__ dinv,
                                                      const unsigned int* __restrict__ bucket_buf,
                                                      const int* __restrict__ gcursor,
                                                      float* __restrict__ s0,
                                                      uint4* __restrict__ f1s_b, int N) {
    __shared__ float accum[128][36];   // pad 32->36: rows 144B (16B-aligned, bank-shift 4)
    int b = blockIdx.x;
    int t = threadIdx.x;
    int base = b * CAP;
    int cnt = min(gcursor[b] - base, CAP);

    for (int i = t; i < 128 * 36; i += 256) ((float*)accum)[i] = 0.f;
    __syncthreads();

    int q = t & 3;
    for (int i = t >> 2; i < cnt; i += 64) {
        unsigned int v = bucket_buf[base + i];
        int srcn = (int)(v >> 7);
        int dl = (int)(v & 127u);
        uint4 r = hs_b[(size_t)srcn * 4 + q];
        float* a = &accum[dl][8 * q];
        atomicAdd(&a[0], bflo(r.x)); atomicAdd(&a[1], bfhi(r.x));
        atomicAdd(&a[2], bflo(r.y)); atomicAdd(&a[3], bfhi(r.y));
        atomicAdd(&a[4], bflo(r.z)); atomicAdd(&a[5], bfhi(r.z));
        atomicAdd(&a[6], bflo(r.w)); atomicAdd(&a[7], bfhi(r.w));
    }
    __syncthreads();

    // epilogue: 2 threads/node, 16 features each
    int ln = t >> 1, half = t & 1;
    int node = (b << 7) + ln;
    if (node >= N) return;
    float di = dinv[node];
    int fb = 16 * half;
    float acc[16];
#pragma unroll
    for (int j = 0; j < 16; ++j) acc[j] = accum[ln][fb + j];
    const float* hrow = h + (size_t)node * HD + fb;
    float f[16];
#pragma unroll
    for (int j = 0; j < 16; ++j) f[j] = fmaf(di, acc[j], hrow[j]);
    float4* sp = (float4*)(s0 + (size_t)node * HD + fb);
    float4 s0v = {acc[0], acc[1], acc[2], acc[3]};
    float4 s1v = {acc[4], acc[5], acc[6], acc[7]};
    float4 s2v = {acc[8], acc[9], acc[10], acc[11]};
    float4 s3v = {acc[12], acc[13], acc[14], acc[15]};
    sp[0] = s0v; sp[1] = s1v; sp[2] = s2v; sp[3] = s3v;
    uint4 u0, u1;
    u0.x = pack2(di * f[0], di * f[1]);  u0.y = pack2(di * f[2], di * f[3]);
    u0.z = pack2(di * f[4], di * f[5]);  u0.w = pack2(di * f[6], di * f[7]);
    u1.x = pack2(di * f[8], di * f[9]);  u1.y = pack2(di * f[10], di * f[11]);
    u1.z = pack2(di * f[12], di * f[13]); u1.w = pack2(di * f[14], di * f[15]);
    f1s_b[(size_t)node * 4 + 2 * half]     = u0;
    f1s_b[(size_t)node * 4 + 2 * half + 1] = u1;
}

// ---------------- fused gather #2 + MFMA epilogue, edge-parallel per bucket ----------------
// t1 gathered edge-parallel into LDS accum (as gather1), then R5's MFMA
// epilogue: wave w handles nodes [w*32, w*32+32) as two 16-node tiles.
// Identity: p_i = y_i@W2 + b2 with y_i = al_i*h + be_i*a + ga_i*b;
// res = (sum_i score_i*y_i)@Wc. hi/lo bf16 split = fp32-equivalent.
__global__ __launch_bounds__(256) void final_kernel(const float* __restrict__ h,
                                                    const float* __restrict__ s0,
                                                    const uint4* __restrict__ f1s_b,
                                                    const float* __restrict__ dinv,
                                                    const unsigned int* __restrict__ bucket_buf,
                                                    const int* __restrict__ gcursor,
                                                    const float* __restrict__ W2,
                                                    const float* __restrict__ b2,
                                                    const float* __restrict__ Wc,
                                                    const float* __restrict__ bc,
                                                    const float* __restrict__ wbern,
                                                    float* __restrict__ out, int N) {
    __shared__ float accum[128][36];
    __shared__ unsigned short w2h[32][40];
    __shared__ unsigned short w2l[32][40];

    int b = blockIdx.x;
    int t = threadIdx.x;
    int base = b * CAP;
    int cnt = min(gcursor[b] - base, CAP);

    for (int i = t; i < HD * HD; i += 256) {
        int k = i >> 5, j = i & 31;
        float x = W2[i];
        unsigned int uh = f2bf(x);
        float xh = __uint_as_float(uh << 16);
        w2h[j][k] = (unsigned short)uh;
        w2l[j][k] = (unsigned short)f2bf(x - xh);
    }
    for (int i = t; i < 128 * 36; i += 256) ((float*)accum)[i] = 0.f;
    __syncthreads();

    int q = t & 3;
    for (int i = t >> 2; i < cnt; i += 64) {
        unsigned int v = bucket_buf[base + i];
        int srcn = (int)(v >> 7);
        int dl = (int)(v & 127u);
        uint4 r = f1s_b[(size_t)srcn * 4 + q];
        float* a = &accum[dl][8 * q];
        atomicAdd(&a[0], bflo(r.x)); atomicAdd(&a[1], bfhi(r.x));
        atomicAdd(&a[2], bflo(r.y)); atomicAdd(&a[3], bfhi(r.y));
        atomicAdd(&a[4], bflo(r.z)); atomicAdd(&a[5], bfhi(r.z));
        atomicAdd(&a[6], bflo(r.w)); atomicAdd(&a[7], bfhi(r.w));
    }
    __syncthreads();

    // ---- Bern coefficients (uniform over nodes) ----
    float al[NL], be[NL], ga[NL];
#pragma unroll
    for (int i = 0; i < NL; ++i) {
        float wa = 0.25f * fmaxf(wbern[i * 3 + 0], 0.0f);
        float wb = 0.50f * fmaxf(wbern[i * 3 + 1], 0.0f);
        float wc = 0.25f * fmaxf(wbern[i * 3 + 2], 0.0f);
        al[i] = wa + wb + wc;          // coeff of h
        be[i] = wa + wb - 3.0f * wc;   // coeff of a
        ga[i] = wa - wb + wc;          // coeff of b
    }

    int w = t >> 6;
    int l = t & 63;
    int g = l >> 4;             // k-block owner
    int c = l & 15;             // node within 16-node tile / A-row j
    int kb = 8 * g;

#pragma unroll
    for (int sTile = 0; sTile < 2; ++sTile) {
        int ln = w * 32 + sTile * 16 + c;
        int node = (b << 7) + ln;
        int nc = (node < N) ? node : (N - 1);

        float di = dinv[nc];
        const float4* hp = (const float4*)(h + (size_t)nc * HD + kb);
        const float4* sp = (const float4*)(s0 + (size_t)nc * HD + kb);
        float4 h0 = hp[0], h1v = hp[1];
        float4 sA = sp[0], sB = sp[1];
        float hv[8] = {h0.x, h0.y, h0.z, h0.w, h1v.x, h1v.y, h1v.z, h1v.w};
        float av[8] = {di * sA.x, di * sA.y, di * sA.z, di * sA.w,
                       di * sB.x, di * sB.y, di * sB.z, di * sB.w};
        float bv[8];
#pragma unroll
        for (int k = 0; k < 8; ++k) bv[k] = di * accum[ln][kb + k];

        float y0[8], y1[8], y2[8];
#pragma unroll
        for (int k = 0; k < 8; ++k) {
            y0[k] = fmaf(ga[0], bv[k], fmaf(be[0], av[k], al[0] * hv[k]));
            y1[k] = fmaf(ga[1], bv[k], fmaf(be[1], av[k], al[1] * hv[k]));
            y2[k] = fmaf(ga[2], bv[k], fmaf(be[2], av[k], al[2] * hv[k]));
        }

        bf16x8 fbh[4], fbl[4];
        pack_hilo(hv, fbh[0], fbl[0]);
        pack_hilo(y0, fbh[1], fbl[1]);
        pack_hilo(y1, fbh[2], fbl[2]);
        pack_hilo(y2, fbh[3], fbl[3]);

        f32x4 D[4][2];
#pragma unroll
        for (int m = 0; m < 4; ++m)
#pragma unroll
            for (int jt = 0; jt < 2; ++jt) { D[m][jt][0] = 0.f; D[m][jt][1] = 0.f; D[m][jt][2] = 0.f; D[m][jt][3] = 0.f; }
#pragma unroll
        for (int jt = 0; jt < 2; ++jt) {
            bf16x8 ah = *(const bf16x8*)&w2h[jt * 16 + c][kb];
            bf16x8 alo = *(const bf16x8*)&w2l[jt * 16 + c][kb];
#pragma unroll
            for (int m = 0; m < 4; ++m) {
                D[m][jt] = __builtin_amdgcn_mfma_f32_16x16x32_bf16(ah,  fbh[m], D[m][jt], 0, 0, 0);
                D[m][jt] = __builtin_amdgcn_mfma_f32_16x16x32_bf16(alo, fbh[m], D[m][jt], 0, 0, 0);
                D[m][jt] = __builtin_amdgcn_mfma_f32_16x16x32_bf16(ah,  fbl[m], D[m][jt], 0, 0, 0);
            }
        }

        float4 b2lo = ((const float4*)b2)[g];
        float4 b2hi = ((const float4*)b2)[4 + g];
        float b2j[2][4] = {{b2lo.x, b2lo.y, b2lo.z, b2lo.w}, {b2hi.x, b2hi.y, b2hi.z, b2hi.w}};
        float lg[NL] = {0.f, 0.f, 0.f};
#pragma unroll
        for (int jt = 0; jt < 2; ++jt) {
#pragma unroll
            for (int r = 0; r < 4; ++r) {
                float xp = fast_tanh(D[0][jt][r] + b2j[jt][r]);
                lg[0] = fmaf(fast_tanh(D[1][jt][r] + b2j[jt][r]), xp, lg[0]);
                lg[1] = fmaf(fast_tanh(D[2][jt][r] + b2j[jt][r]), xp, lg[1]);
                lg[2] = fmaf(fast_tanh(D[3][jt][r] + b2j[jt][r]), xp, lg[2]);
            }
        }
#pragma unroll
        for (int i = 0; i < NL; ++i) {
            lg[i] += __shfl_xor(lg[i], 16);
            lg[i] += __shfl_xor(lg[i], 32);
        }

        float m = fmaxf(lg[0], fmaxf(lg[1], lg[2]));
        float e0 = __expf(lg[0] - m), e1 = __expf(lg[1] - m), e2 = __expf(lg[2] - m);
        float inv = 1.0f / (e0 + e1 + e2);
        float s0c = e0 * inv, s1c = e1 * inv, s2c = e2 * inv;

        float o0 = 0.f, o1 = 0.f;
        const float2* wcp = (const float2*)Wc;
#pragma unroll
        for (int k = 0; k < 8; ++k) {
            float z = fmaf(s2c, y2[k], fmaf(s1c, y1[k], s0c * y0[k]));
            float2 wck = wcp[kb + k];
            o0 = fmaf(z, wck.x, o0);
            o1 = fmaf(z, wck.y, o1);
        }
        o0 += __shfl_xor(o0, 16); o0 += __shfl_xor(o0, 32);
        o1 += __shfl_xor(o1, 16); o1 += __shfl_xor(o1, 32);

        if (g == 0 && node < N) {
            float2 o = {bc[0] + o0, bc[1] + o1};
            ((float2*)out)[node] = o;
        }
    }
}

extern "C" void kernel_launch(void* const* d_in, const int* in_sizes, int n_in,
                              void* d_out, int out_size, void* d_ws, size_t ws_size,
                              hipStream_t stream) {
    const float* feature = (const float*)d_in[0];
    const float* W1 = (const float*)d_in[1];
    const float* b1 = (const float*)d_in[2];
    const float* W2 = (const float*)d_in[3];
    const float* b2 = (const float*)d_in[4];
    const float* Wc = (const float*)d_in[5];
    const float* bc = (const float*)d_in[6];
    const float* wbern = (const float*)d_in[7];
    const int* src = (const int*)d_in[8];
    const int* dst = (const int*)d_in[9];

    const int N = in_sizes[0] / FIN;   // 100000
    const int E = in_sizes[8];         // 1600000
    const int B = (N + 127) >> 7;      // 782 buckets

    // workspace layout
    char* p = (char*)d_ws;
    size_t Np = ((size_t)N + 255) & ~(size_t)255;
    size_t N32 = (size_t)N * HD;
    int* gcursor   = (int*)p;              p += ((size_t)BMAX) * 4;
    float* dinv    = (float*)p;            p += Np * 4;
    unsigned int* bucket_buf = (unsigned int*)p;  p += (size_t)B * CAP * 4;  // packed (src<<7|dstLow)
    float* h    = (float*)p;               p += N32 * 4;
    float* s0   = (float*)p;               p += N32 * 4;
    uint4* hs_b = (uint4*)p;               p += N32 * 2;   // bf16, 64B/row
    uint4* f1s_b= (uint4*)p;               p += N32 * 2;

    int bM = (N + 63) / 64;                // 64 nodes per block (4 waves x 16)
    int nTiles = (E + TILE - 1) / TILE;

    init_kernel<<<(B + 255) / 256, 256, 0, stream>>>(gcursor, B);
    partition_kernel<<<nTiles, 256, 0, stream>>>(src, dst, gcursor, bucket_buf, E);
    deg_kernel<<<B, 256, 0, stream>>>(bucket_buf, gcursor, dinv, N);

    mlp_kernel<<<bM, 256, 0, stream>>>(feature, W1, b1, W2, b2, dinv, h, hs_b, N);

    gather1_kernel<<<B, 256, 0, stream>>>(h, hs_b, dinv, bucket_buf, gcursor, s0, f1s_b, N);

    final_kernel<<<B, 256, 0, stream>>>(h, s0, f1s_b, dinv, bucket_buf, gcursor,
                                        W2, b2, Wc, bc, wbern, (float*)d_out, N);
}

// Round 11
// 185.479 us; speedup vs baseline: 4.3380x; 4.3380x over previous
//
#include <hip/hip_runtime.h>
#include <math.h>

#define HD 32      // hidden dim
#define FIN 64     // input features
#define NL 3       // num BernConv layers
#define NC 2       // num classes

#define TILE 4096  // edges per partition tile
#define CAP  3072  // max edges per bucket (mean ~2046, 12 sigma margin)
#define BMAX 1024  // max buckets (N <= 131072 with 128 nodes/bucket)

typedef __attribute__((ext_vector_type(8))) short bf16x8;
typedef __attribute__((ext_vector_type(4))) float f32x4;

// fast tanh; |rel err| ~1e-7, threshold 7e-2
__device__ __forceinline__ float fast_tanh(float x) {
    float e = __expf(2.0f * x);
    return 1.0f - 2.0f * __builtin_amdgcn_rcpf(e + 1.0f);
}

// fp32 -> bf16 bits with round-to-nearest-even (values are finite here)
__device__ __forceinline__ unsigned int f2bf(float f) {
    unsigned int u = __float_as_uint(f);
    return (u + 0x7fffu + ((u >> 16) & 1u)) >> 16;
}
__device__ __forceinline__ unsigned int pack2(float lo, float hi) {
    return f2bf(lo) | (f2bf(hi) << 16);
}
// bf16 pair -> fp32 (exact, just bit shifts)
__device__ __forceinline__ float bflo(unsigned int u) { return __uint_as_float(u << 16); }
__device__ __forceinline__ float bfhi(unsigned int u) { return __uint_as_float(u & 0xffff0000u); }

// split x into bf16 hi + bf16 lo (residual); hi+lo recovers x to ~2^-17 rel
__device__ __forceinline__ void pack_hilo(const float* v, bf16x8& hi, bf16x8& lo) {
#pragma unroll
    for (int e = 0; e < 8; ++e) {
        unsigned int uh = f2bf(v[e]);
        float xh = __uint_as_float(uh << 16);
        unsigned int ul = f2bf(v[e] - xh);
        hi[e] = (short)uh;
        lo[e] = (short)ul;
    }
}

// ---------------- LDS-staged partition: bucket edges by dst>>7 ----------------
// gcursor holds RELATIVE per-bucket counts (memset-0 by host; no init kernel).
__global__ __launch_bounds__(256) void partition_kernel(const int* __restrict__ src,
                                                        const int* __restrict__ dst,
                                                        int* __restrict__ gcursor,
                                                        unsigned int* __restrict__ bucket_buf,
                                                        int E) {
    __shared__ unsigned int vals[TILE];
    __shared__ unsigned short bid[TILE];
    __shared__ int hist[BMAX];
    __shared__ int lcur[BMAX];
    __shared__ int goff[BMAX];
    __shared__ int sc[256];
    int t = threadIdx.x;
    int tile_base = blockIdx.x * TILE;
    int n_tile = min(TILE, E - tile_base);

    for (int i = t; i < BMAX; i += 256) hist[i] = 0;
    __syncthreads();

    unsigned int pk[TILE / 256];
    int bk[TILE / 256];
#pragma unroll
    for (int k = 0; k < TILE / 256; ++k) {
        int e = tile_base + k * 256 + t;
        if (e < E) {
            int s = src[e], d = dst[e];
            int b = d >> 7;
            pk[k] = ((unsigned)s << 7) | (unsigned)(d & 127);
            bk[k] = b;
            atomicAdd(&hist[b], 1);
        } else bk[k] = -1;
    }
    __syncthreads();

    int base4 = t * 4;
    int sum4 = hist[base4] + hist[base4 + 1] + hist[base4 + 2] + hist[base4 + 3];
    sc[t] = sum4;
    __syncthreads();
    for (int off = 1; off < 256; off <<= 1) {
        int v = (t >= off) ? sc[t - off] : 0;
        __syncthreads();
        sc[t] += v;
        __syncthreads();
    }
    int run = sc[t] - sum4;
#pragma unroll
    for (int j = 0; j < 4; ++j) {
        int tmp = hist[base4 + j];
        hist[base4 + j] = run;
        lcur[base4 + j] = run;
        run += tmp;
    }
    __syncthreads();

#pragma unroll
    for (int k = 0; k < TILE / 256; ++k) {
        if (bk[k] >= 0) {
            int pos = atomicAdd(&lcur[bk[k]], 1);
            vals[pos] = pk[k];
            bid[pos] = (unsigned short)bk[k];
        }
    }
    __syncthreads();

    for (int b = t; b < BMAX; b += 256) {
        int cnt = lcur[b] - hist[b];
        goff[b] = (cnt > 0) ? (b * CAP + atomicAdd(&gcursor[b], cnt)) : 0;
    }
    __syncthreads();

    for (int i = t; i < n_tile; i += 256) {
        int b = bid[i];
        int addr = goff[b] + (i - hist[b]);
        if (addr < (b + 1) * CAP)
            bucket_buf[addr] = vals[i];
    }
}

// ---------------- per-bucket CSR build (in place) ----------------
__global__ __launch_bounds__(256) void bucket_csr_kernel(unsigned int* bucket_buf,
                                                         const int* __restrict__ gcursor,
                                                         int* __restrict__ row_start,
                                                         int* __restrict__ degA,
                                                         float* __restrict__ dinv,
                                                         int N) {
    __shared__ int ldeg[128], lexc[128], lcur2[128];
    __shared__ int colLDS[CAP];
    int b = blockIdx.x;
    int t = threadIdx.x;
    int base = b * CAP;
    int cnt = min(gcursor[b], CAP);

    if (t < 128) ldeg[t] = 0;
    __syncthreads();
    for (int i = t; i < cnt; i += 256)
        atomicAdd(&ldeg[bucket_buf[base + i] & 127], 1);
    __syncthreads();

    if (t < 128) lexc[t] = ldeg[t];
    __syncthreads();
    for (int off = 1; off < 128; off <<= 1) {
        int v = (t >= off && t < 128) ? lexc[t - off] : 0;
        __syncthreads();
        if (t < 128) lexc[t] += v;
        __syncthreads();
    }
    if (t < 128) {
        int ex = lexc[t] - ldeg[t];
        lcur2[t] = ex;
        int node = (b << 7) + t;
        if (node < N) {
            row_start[node] = base + ex;
            degA[node] = ldeg[t];
            dinv[node] = rsqrtf(fmaxf((float)ldeg[t], 1.0f));
        }
    }
    __syncthreads();

    for (int i = t; i < cnt; i += 256) {
        unsigned int v = bucket_buf[base + i];
        int pos = atomicAdd(&lcur2[(int)(v & 127)], 1);
        colLDS[pos] = (int)(v >> 7);
    }
    __syncthreads();
    for (int i = t; i < cnt; i += 256)
        bucket_buf[base + i] = (unsigned int)colLDS[i];   // now = col[]
}

// ---------------- MLP in via MFMA: h = relu(feat@W1+b1)@W2+b2 ----------------
__global__ __launch_bounds__(256) void mlp_kernel(const float* __restrict__ feat,
                                                  const float* __restrict__ W1,
                                                  const float* __restrict__ b1,
                                                  const float* __restrict__ W2,
                                                  const float* __restrict__ b2,
                                                  const float* __restrict__ dinv,
                                                  float* __restrict__ hout,
                                                  uint4* __restrict__ hs_b, int N) {
    __shared__ unsigned short w1t[32][72];      // W1^T [j][k], pad 64->72
    __shared__ unsigned short w2t[32][40];      // W2^T [j][k], pad 32->40
    __shared__ unsigned short h1t[4][16][40];   // per-wave relu(h1) [row][j] bf16
    __shared__ unsigned short h2t[4][16][40];   // per-wave dinv*h2   [row][j] bf16

    int lt = threadIdx.x;
    for (int i = lt; i < FIN * HD; i += 256) {
        int k = i >> 5, j = i & 31;
        w1t[j][k] = (unsigned short)f2bf(W1[i]);
    }
    for (int i = lt; i < HD * HD; i += 256) {
        int k = i >> 5, j = i & 31;
        w2t[j][k] = (unsigned short)f2bf(W2[i]);
    }
    __syncthreads();

    int w = lt >> 6;
    int l = lt & 63;
    int g = l >> 4;
    int c = l & 15;
    int base = blockIdx.x * 64 + w * 16;

    int row = base + c;
    int rowc = (row < N) ? row : (N - 1);
    const float* fr = feat + (size_t)rowc * FIN;
    bf16x8 a1[2];
#pragma unroll
    for (int ks = 0; ks < 2; ++ks) {
        const float4* p = (const float4*)(fr + ks * 32 + 8 * g);
        float4 u0 = p[0], u1 = p[1];
        bf16x8 a;
        a[0] = (short)f2bf(u0.x); a[1] = (short)f2bf(u0.y);
        a[2] = (short)f2bf(u0.z); a[3] = (short)f2bf(u0.w);
        a[4] = (short)f2bf(u1.x); a[5] = (short)f2bf(u1.y);
        a[6] = (short)f2bf(u1.z); a[7] = (short)f2bf(u1.w);
        a1[ks] = a;
    }

    f32x4 acc[2];
#pragma unroll
    for (int nt = 0; nt < 2; ++nt) { acc[nt][0] = 0.f; acc[nt][1] = 0.f; acc[nt][2] = 0.f; acc[nt][3] = 0.f; }
#pragma unroll
    for (int nt = 0; nt < 2; ++nt) {
#pragma unroll
        for (int ks = 0; ks < 2; ++ks) {
            bf16x8 b = *(const bf16x8*)&w1t[nt * 16 + c][ks * 32 + 8 * g];
            acc[nt] = __builtin_amdgcn_mfma_f32_16x16x32_bf16(a1[ks], b, acc[nt], 0, 0, 0);
        }
    }

    float b1v0 = b1[c], b1v1 = b1[16 + c];
#pragma unroll
    for (int r = 0; r < 4; ++r) {
        h1t[w][4 * g + r][c]      = (unsigned short)f2bf(fmaxf(acc[0][r] + b1v0, 0.0f));
        h1t[w][4 * g + r][16 + c] = (unsigned short)f2bf(fmaxf(acc[1][r] + b1v1, 0.0f));
    }
    __syncthreads();

    bf16x8 a2 = *(const bf16x8*)&h1t[w][c][8 * g];
    f32x4 acc2[2];
#pragma unroll
    for (int nt = 0; nt < 2; ++nt) { acc2[nt][0] = 0.f; acc2[nt][1] = 0.f; acc2[nt][2] = 0.f; acc2[nt][3] = 0.f; }
#pragma unroll
    for (int nt = 0; nt < 2; ++nt) {
        bf16x8 b = *(const bf16x8*)&w2t[nt * 16 + c][8 * g];
        acc2[nt] = __builtin_amdgcn_mfma_f32_16x16x32_bf16(a2, b, acc2[nt], 0, 0, 0);
    }

    float b2v0 = b2[c], b2v1 = b2[16 + c];
#pragma unroll
    for (int r = 0; r < 4; ++r) {
        int rr = base + 4 * g + r;
        int rc = (rr < N) ? rr : (N - 1);
        float dv = dinv[rc];
        float v0 = acc2[0][r] + b2v0;
        float v1 = acc2[1][r] + b2v1;
        if (rr < N) {
            hout[(size_t)rr * HD + c]      = v0;
            hout[(size_t)rr * HD + 16 + c] = v1;
        }
        h2t[w][4 * g + r][c]      = (unsigned short)f2bf(dv * v0);
        h2t[w][4 * g + r][16 + c] = (unsigned short)f2bf(dv * v1);
    }
    __syncthreads();

    int nrow = base + c;
    if (nrow < N) {
        uint4 u = *(const uint4*)&h2t[w][c][8 * g];
        hs_b[(size_t)nrow * 4 + g] = u;
    }
}

// ---------------- gather #1: acc = sum hs[col];
//                  f1s_b = bf16(dinv[n]*(h[n] + dinv[n]*acc)) ----------------
// 4 lanes/node (quad = one merged 64B line request), x4 unroll.
// NO s0 output: final recovers av = di*acc from f1s_b itself
// (av = f1s/di - h), deleting 25.6MB of s0 stream traffic.
__global__ __launch_bounds__(256) void gather1_kernel(const float* __restrict__ h,
                                                      const uint4* __restrict__ hs_b,
                                                      const float* __restrict__ dinv,
                                                      const int* __restrict__ row_start,
                                                      const int* __restrict__ deg,
                                                      const int* __restrict__ col,
                                                      uint4* __restrict__ f1s_b, int N) {
    int t = blockIdx.x * 256 + threadIdx.x;
    int n = t >> 2;
    if (n >= N) return;
    int q = t & 3;
    int s = row_start[n];
    int e_end = s + deg[n];
    float acc[8] = {0.f, 0.f, 0.f, 0.f, 0.f, 0.f, 0.f, 0.f};
    int e = s;
    for (; e + 4 <= e_end; e += 4) {
        int c0 = col[e], c1 = col[e + 1], c2 = col[e + 2], c3 = col[e + 3];
        uint4 v0 = hs_b[(size_t)c0 * 4 + q];
        uint4 v1 = hs_b[(size_t)c1 * 4 + q];
        uint4 v2 = hs_b[(size_t)c2 * 4 + q];
        uint4 v3 = hs_b[(size_t)c3 * 4 + q];
        acc[0] += (bflo(v0.x) + bflo(v1.x)) + (bflo(v2.x) + bflo(v3.x));
        acc[1] += (bfhi(v0.x) + bfhi(v1.x)) + (bfhi(v2.x) + bfhi(v3.x));
        acc[2] += (bflo(v0.y) + bflo(v1.y)) + (bflo(v2.y) + bflo(v3.y));
        acc[3] += (bfhi(v0.y) + bfhi(v1.y)) + (bfhi(v2.y) + bfhi(v3.y));
        acc[4] += (bflo(v0.z) + bflo(v1.z)) + (bflo(v2.z) + bflo(v3.z));
        acc[5] += (bfhi(v0.z) + bfhi(v1.z)) + (bfhi(v2.z) + bfhi(v3.z));
        acc[6] += (bflo(v0.w) + bflo(v1.w)) + (bflo(v2.w) + bflo(v3.w));
        acc[7] += (bfhi(v0.w) + bfhi(v1.w)) + (bfhi(v2.w) + bfhi(v3.w));
    }
    for (; e < e_end; ++e) {
        int c = col[e];
        uint4 v = hs_b[(size_t)c * 4 + q];
        acc[0] += bflo(v.x); acc[1] += bfhi(v.x);
        acc[2] += bflo(v.y); acc[3] += bfhi(v.y);
        acc[4] += bflo(v.z); acc[5] += bfhi(v.z);
        acc[6] += bflo(v.w); acc[7] += bfhi(v.w);
    }
    float di = dinv[n];
    const float4* h4 = (const float4*)h;
    float4 ha = h4[(size_t)n * 8 + 2 * q];
    float4 hb = h4[(size_t)n * 8 + 2 * q + 1];
    float f[8] = {fmaf(di, acc[0], ha.x), fmaf(di, acc[1], ha.y),
                  fmaf(di, acc[2], ha.z), fmaf(di, acc[3], ha.w),
                  fmaf(di, acc[4], hb.x), fmaf(di, acc[5], hb.y),
                  fmaf(di, acc[6], hb.z), fmaf(di, acc[7], hb.w)};
    uint4 u;
    u.x = pack2(di * f[0], di * f[1]);
    u.y = pack2(di * f[2], di * f[3]);
    u.z = pack2(di * f[4], di * f[5]);
    u.w = pack2(di * f[6], di * f[7]);
    f1s_b[(size_t)n * 4 + q] = u;
}

// ---------------- fused gather #2 + MFMA epilogue ----------------
// Identity: p_i = y_i@W2 + b2 with y_i = al_i*h + be_i*a + ga_i*b (a=d*s0, b=d*t1);
// res = (sum_i score_i*y_i)@Wc. A = W2^T (LDS), B = per-node data fragments.
// hi/lo bf16 split on BOTH operands (3 MFMAs/product) = fp32-equivalent.
// av is RECOVERED from the node's own f1s_b row: f1s = bf16(di*(h + di*s0))
// -> av = di*s0 = f1s/di - h  (bf16 err ~2^-9|f| ~ 0.004, well under budget).
// This deletes the s0 buffer (25.6MB stream) entirely.
__global__ __launch_bounds__(256) void final_kernel(const float* __restrict__ h,
                                                    const uint4* __restrict__ f1s_b,
                                                    const float* __restrict__ dinv,
                                                    const int* __restrict__ row_start,
                                                    const int* __restrict__ deg,
                                                    const int* __restrict__ col,
                                                    const float* __restrict__ W2,
                                                    const float* __restrict__ b2,
                                                    const float* __restrict__ Wc,
                                                    const float* __restrict__ bc,
                                                    const float* __restrict__ wbern,
                                                    float* __restrict__ out, int N) {
    __shared__ unsigned short w2h[32][40];   // bf16 hi of W2^T [j][k]
    __shared__ unsigned short w2l[32][40];   // bf16 lo (residual)

    int lt = threadIdx.x;
    for (int i = lt; i < HD * HD; i += 256) {
        int k = i >> 5, j = i & 31;
        float x = W2[i];
        unsigned int uh = f2bf(x);
        float xh = __uint_as_float(uh << 16);
        w2h[j][k] = (unsigned short)uh;
        w2l[j][k] = (unsigned short)f2bf(x - xh);
    }
    __syncthreads();

    int w = lt >> 6;
    int l = lt & 63;
    int g = l >> 4;             // k-block owner
    int c = l & 15;             // node within wave tile / A-row j
    int node = blockIdx.x * 64 + w * 16 + c;
    int nc = (node < N) ? node : (N - 1);
    int kb = 8 * g;

    // ---- gather t1 for (node, k-block): 4 chains in flight ----
    int s = row_start[nc];
    int e_end = s + deg[nc];
    float acc[8] = {0.f, 0.f, 0.f, 0.f, 0.f, 0.f, 0.f, 0.f};
    int e = s;
    for (; e + 4 <= e_end; e += 4) {
        int c0 = col[e], c1 = col[e + 1], c2 = col[e + 2], c3 = col[e + 3];
        uint4 v0 = f1s_b[(size_t)c0 * 4 + g];
        uint4 v1 = f1s_b[(size_t)c1 * 4 + g];
        uint4 v2 = f1s_b[(size_t)c2 * 4 + g];
        uint4 v3 = f1s_b[(size_t)c3 * 4 + g];
        acc[0] += (bflo(v0.x) + bflo(v1.x)) + (bflo(v2.x) + bflo(v3.x));
        acc[1] += (bfhi(v0.x) + bfhi(v1.x)) + (bfhi(v2.x) + bfhi(v3.x));
        acc[2] += (bflo(v0.y) + bflo(v1.y)) + (bflo(v2.y) + bflo(v3.y));
        acc[3] += (bfhi(v0.y) + bfhi(v1.y)) + (bfhi(v2.y) + bfhi(v3.y));
        acc[4] += (bflo(v0.z) + bflo(v1.z)) + (bflo(v2.z) + bflo(v3.z));
        acc[5] += (bfhi(v0.z) + bfhi(v1.z)) + (bfhi(v2.z) + bfhi(v3.z));
        acc[6] += (bflo(v0.w) + bflo(v1.w)) + (bflo(v2.w) + bflo(v3.w));
        acc[7] += (bfhi(v0.w) + bfhi(v1.w)) + (bfhi(v2.w) + bfhi(v3.w));
    }
    for (; e < e_end; ++e) {
        int cc = col[e];
        uint4 v = f1s_b[(size_t)cc * 4 + g];
        acc[0] += bflo(v.x); acc[1] += bfhi(v.x);
        acc[2] += bflo(v.y); acc[3] += bfhi(v.y);
        acc[4] += bflo(v.z); acc[5] += bfhi(v.z);
        acc[6] += bflo(v.w); acc[7] += bfhi(v.w);
    }

    float di = dinv[nc];
    float rdi = 1.0f / di;
    const float4* hp = (const float4*)(h + (size_t)nc * HD + kb);
    float4 h0 = hp[0], h1v = hp[1];
    float hv[8] = {h0.x, h0.y, h0.z, h0.w, h1v.x, h1v.y, h1v.z, h1v.w};

    // own f1s row -> av recovery (likely L2-hot: same table the gather pulls)
    uint4 fv = f1s_b[(size_t)nc * 4 + g];
    float fl[8] = {bflo(fv.x), bfhi(fv.x), bflo(fv.y), bfhi(fv.y),
                   bflo(fv.z), bfhi(fv.z), bflo(fv.w), bfhi(fv.w)};
    float av[8];
#pragma unroll
    for (int k = 0; k < 8; ++k) av[k] = fmaf(fl[k], rdi, -hv[k]);

    float bv[8];
#pragma unroll
    for (int k = 0; k < 8; ++k) bv[k] = di * acc[k];

    // ---- Bern coefficients (uniform over nodes) ----
    float al[NL], be[NL], ga[NL];
#pragma unroll
    for (int i = 0; i < NL; ++i) {
        float wa = 0.25f * fmaxf(wbern[i * 3 + 0], 0.0f);
        float wb = 0.50f * fmaxf(wbern[i * 3 + 1], 0.0f);
        float wc = 0.25f * fmaxf(wbern[i * 3 + 2], 0.0f);
        al[i] = wa + wb + wc;          // coeff of h
        be[i] = wa + wb - 3.0f * wc;   // coeff of a
        ga[i] = wa - wb + wc;          // coeff of b
    }

    // ---- y_i fp32 (kept for the exact z->Wc path) ----
    float y0[8], y1[8], y2[8];
#pragma unroll
    for (int k = 0; k < 8; ++k) {
        y0[k] = fmaf(ga[0], bv[k], fmaf(be[0], av[k], al[0] * hv[k]));
        y1[k] = fmaf(ga[1], bv[k], fmaf(be[1], av[k], al[1] * hv[k]));
        y2[k] = fmaf(ga[2], bv[k], fmaf(be[2], av[k], al[2] * hv[k]));
    }

    // ---- B fragments (data): hi/lo pairs for h, y0, y1, y2 ----
    bf16x8 fbh[4], fbl[4];
    pack_hilo(hv, fbh[0], fbl[0]);
    pack_hilo(y0, fbh[1], fbl[1]);
    pack_hilo(y1, fbh[2], fbl[2]);
    pack_hilo(y2, fbh[3], fbl[3]);

    // ---- MFMA: D[m][jt] = W2^T(jt-tile) @ data_m ; 3 products per pair ----
    f32x4 D[4][2];
#pragma unroll
    for (int m = 0; m < 4; ++m)
#pragma unroll
        for (int jt = 0; jt < 2; ++jt) { D[m][jt][0] = 0.f; D[m][jt][1] = 0.f; D[m][jt][2] = 0.f; D[m][jt][3] = 0.f; }
#pragma unroll
    for (int jt = 0; jt < 2; ++jt) {
        bf16x8 ah = *(const bf16x8*)&w2h[jt * 16 + c][kb];
        bf16x8 alo = *(const bf16x8*)&w2l[jt * 16 + c][kb];
#pragma unroll
        for (int m = 0; m < 4; ++m) {
            D[m][jt] = __builtin_amdgcn_mfma_f32_16x16x32_bf16(ah,  fbh[m], D[m][jt], 0, 0, 0);
            D[m][jt] = __builtin_amdgcn_mfma_f32_16x16x32_bf16(alo, fbh[m], D[m][jt], 0, 0, 0);
            D[m][jt] = __builtin_amdgcn_mfma_f32_16x16x32_bf16(ah,  fbl[m], D[m][jt], 0, 0, 0);
        }
    }

    // ---- bias + tanh; logit partials: lane holds j = jt*16 + 4g + r, node c ----
    float4 b2lo = ((const float4*)b2)[g];
    float4 b2hi = ((const float4*)b2)[4 + g];
    float b2j[2][4] = {{b2lo.x, b2lo.y, b2lo.z, b2lo.w}, {b2hi.x, b2hi.y, b2hi.z, b2hi.w}};
    float lg[NL] = {0.f, 0.f, 0.f};
#pragma unroll
    for (int jt = 0; jt < 2; ++jt) {
#pragma unroll
        for (int r = 0; r < 4; ++r) {
            float xp = fast_tanh(D[0][jt][r] + b2j[jt][r]);
            lg[0] = fmaf(fast_tanh(D[1][jt][r] + b2j[jt][r]), xp, lg[0]);
            lg[1] = fmaf(fast_tanh(D[2][jt][r] + b2j[jt][r]), xp, lg[1]);
            lg[2] = fmaf(fast_tanh(D[3][jt][r] + b2j[jt][r]), xp, lg[2]);
        }
    }
#pragma unroll
    for (int i = 0; i < NL; ++i) {
        lg[i] += __shfl_xor(lg[i], 16);
        lg[i] += __shfl_xor(lg[i], 32);
    }

    // ---- softmax over 3 filters (redundant across g: fine) ----
    float m = fmaxf(lg[0], fmaxf(lg[1], lg[2]));
    float e0 = __expf(lg[0] - m), e1 = __expf(lg[1] - m), e2 = __expf(lg[2] - m);
    float inv = 1.0f / (e0 + e1 + e2);
    float s0c = e0 * inv, s1c = e1 * inv, s2c = e2 * inv;

    // ---- z = sum_i score_i * y_i (fp32), out = bc + z@Wc (reduce over g) ----
    float o0 = 0.f, o1 = 0.f;
    const float2* wcp = (const float2*)Wc;
#pragma unroll
    for (int k = 0; k < 8; ++k) {
        float z = fmaf(s2c, y2[k], fmaf(s1c, y1[k], s0c * y0[k]));
        float2 wck = wcp[kb + k];
        o0 = fmaf(z, wck.x, o0);
        o1 = fmaf(z, wck.y, o1);
    }
    o0 += __shfl_xor(o0, 16); o0 += __shfl_xor(o0, 32);
    o1 += __shfl_xor(o1, 16); o1 += __shfl_xor(o1, 32);

    if (g == 0 && node < N) {
        float2 o = {bc[0] + o0, bc[1] + o1};
        ((float2*)out)[node] = o;
    }
}

extern "C" void kernel_launch(void* const* d_in, const int* in_sizes, int n_in,
                              void* d_out, int out_size, void* d_ws, size_t ws_size,
                              hipStream_t stream) {
    const float* feature = (const float*)d_in[0];
    const float* W1 = (const float*)d_in[1];
    const float* b1 = (const float*)d_in[2];
    const float* W2 = (const float*)d_in[3];
    const float* b2 = (const float*)d_in[4];
    const float* Wc = (const float*)d_in[5];
    const float* bc = (const float*)d_in[6];
    const float* wbern = (const float*)d_in[7];
    const int* src = (const int*)d_in[8];
    const int* dst = (const int*)d_in[9];

    const int N = in_sizes[0] / FIN;   // 100000
    const int E = in_sizes[8];         // 1600000
    const int B = (N + 127) >> 7;      // 782 buckets

    // workspace layout
    char* p = (char*)d_ws;
    size_t Np = ((size_t)N + 255) & ~(size_t)255;
    size_t N32 = (size_t)N * HD;
    int* gcursor   = (int*)p;              p += ((size_t)BMAX) * 4;
    int* row_start = (int*)p;              p += Np * 4;
    int* degA      = (int*)p;              p += Np * 4;
    float* dinv    = (float*)p;            p += Np * 4;
    unsigned int* bucket_buf = (unsigned int*)p;  p += (size_t)B * CAP * 4;  // becomes col[]
    float* h    = (float*)p;               p += N32 * 4;
    uint4* hs_b = (uint4*)p;               p += N32 * 2;   // bf16, 64B/row
    uint4* f1s_b= (uint4*)p;               p += N32 * 2;

    int bG = ((N * 4) + 255) / 256;        // 4 lanes per node
    int bM = (N + 63) / 64;                // 64 nodes per block (4 waves x 16)
    int nTiles = (E + TILE - 1) / TILE;

    hipMemsetAsync(gcursor, 0, (size_t)BMAX * 4, stream);
    partition_kernel<<<nTiles, 256, 0, stream>>>(src, dst, gcursor, bucket_buf, E);
    bucket_csr_kernel<<<B, 256, 0, stream>>>(bucket_buf, gcursor, row_start, degA, dinv, N);

    mlp_kernel<<<bM, 256, 0, stream>>>(feature, W1, b1, W2, b2, dinv, h, hs_b, N);

    const int* col = (const int*)bucket_buf;
    gather1_kernel<<<bG, 256, 0, stream>>>(h, hs_b, dinv, row_start, degA, col, f1s_b, N);

    final_kernel<<<bM, 256, 0, stream>>>(h, f1s_b, dinv, row_start, degA, col,
                                         W2, b2, Wc, bc, wbern, (float*)d_out, N);
}

// Round 12
// 184.963 us; speedup vs baseline: 4.3501x; 1.0028x over previous
//
#include <hip/hip_runtime.h>
#include <math.h>

#define HD 32      // hidden dim
#define FIN 64     // input features
#define NL 3       // num BernConv layers
#define NC 2       // num classes

#define TILE 4096  // edges per partition tile
#define CAP  3072  // max edges per bucket (mean ~2046, 12 sigma margin)
#define BMAX 1024  // max buckets (N <= 131072 with 128 nodes/bucket)

typedef __attribute__((ext_vector_type(8))) short bf16x8;
typedef __attribute__((ext_vector_type(4))) float f32x4;

// fast tanh; |rel err| ~1e-7, threshold 7e-2
__device__ __forceinline__ float fast_tanh(float x) {
    float e = __expf(2.0f * x);
    return 1.0f - 2.0f * __builtin_amdgcn_rcpf(e + 1.0f);
}

// fp32 -> bf16 bits with round-to-nearest-even (values are finite here)
__device__ __forceinline__ unsigned int f2bf(float f) {
    unsigned int u = __float_as_uint(f);
    return (u + 0x7fffu + ((u >> 16) & 1u)) >> 16;
}
__device__ __forceinline__ unsigned int pack2(float lo, float hi) {
    return f2bf(lo) | (f2bf(hi) << 16);
}
// bf16 pair -> fp32 (exact, just bit shifts)
__device__ __forceinline__ float bflo(unsigned int u) { return __uint_as_float(u << 16); }
__device__ __forceinline__ float bfhi(unsigned int u) { return __uint_as_float(u & 0xffff0000u); }

// split x into bf16 hi + bf16 lo (residual); hi+lo recovers x to ~2^-17 rel
__device__ __forceinline__ void pack_hilo(const float* v, bf16x8& hi, bf16x8& lo) {
#pragma unroll
    for (int e = 0; e < 8; ++e) {
        unsigned int uh = f2bf(v[e]);
        float xh = __uint_as_float(uh << 16);
        unsigned int ul = f2bf(v[e] - xh);
        hi[e] = (short)uh;
        lo[e] = (short)ul;
    }
}

// ---------------- LDS-staged partition: bucket edges by dst>>7 ----------------
// gcursor holds RELATIVE per-bucket counts (memset-0 by host; no init kernel).
__global__ __launch_bounds__(256) void partition_kernel(const int* __restrict__ src,
                                                        const int* __restrict__ dst,
                                                        int* __restrict__ gcursor,
                                                        unsigned int* __restrict__ bucket_buf,
                                                        int E) {
    __shared__ unsigned int vals[TILE];
    __shared__ unsigned short bid[TILE];
    __shared__ int hist[BMAX];
    __shared__ int lcur[BMAX];
    __shared__ int goff[BMAX];
    __shared__ int sc[256];
    int t = threadIdx.x;
    int tile_base = blockIdx.x * TILE;
    int n_tile = min(TILE, E - tile_base);

    for (int i = t; i < BMAX; i += 256) hist[i] = 0;
    __syncthreads();

    unsigned int pk[TILE / 256];
    int bk[TILE / 256];
#pragma unroll
    for (int k = 0; k < TILE / 256; ++k) {
        int e = tile_base + k * 256 + t;
        if (e < E) {
            int s = src[e], d = dst[e];
            int b = d >> 7;
            pk[k] = ((unsigned)s << 7) | (unsigned)(d & 127);
            bk[k] = b;
            atomicAdd(&hist[b], 1);
        } else bk[k] = -1;
    }
    __syncthreads();

    int base4 = t * 4;
    int sum4 = hist[base4] + hist[base4 + 1] + hist[base4 + 2] + hist[base4 + 3];
    sc[t] = sum4;
    __syncthreads();
    for (int off = 1; off < 256; off <<= 1) {
        int v = (t >= off) ? sc[t - off] : 0;
        __syncthreads();
        sc[t] += v;
        __syncthreads();
    }
    int run = sc[t] - sum4;
#pragma unroll
    for (int j = 0; j < 4; ++j) {
        int tmp = hist[base4 + j];
        hist[base4 + j] = run;
        lcur[base4 + j] = run;
        run += tmp;
    }
    __syncthreads();

#pragma unroll
    for (int k = 0; k < TILE / 256; ++k) {
        if (bk[k] >= 0) {
            int pos = atomicAdd(&lcur[bk[k]], 1);
            vals[pos] = pk[k];
            bid[pos] = (unsigned short)bk[k];
        }
    }
    __syncthreads();

    for (int b = t; b < BMAX; b += 256) {
        int cnt = lcur[b] - hist[b];
        goff[b] = (cnt > 0) ? (b * CAP + atomicAdd(&gcursor[b], cnt)) : 0;
    }
    __syncthreads();

    for (int i = t; i < n_tile; i += 256) {
        int b = bid[i];
        int addr = goff[b] + (i - hist[b]);
        if (addr < (b + 1) * CAP)
            bucket_buf[addr] = vals[i];
    }
}

// ---------------- per-bucket CSR build (in place) ----------------
__global__ __launch_bounds__(256) void bucket_csr_kernel(unsigned int* bucket_buf,
                                                         const int* __restrict__ gcursor,
                                                         int* __restrict__ row_start,
                                                         int* __restrict__ degA,
                                                         float* __restrict__ dinv,
                                                         int N) {
    __shared__ int ldeg[128], lexc[128], lcur2[128];
    __shared__ int colLDS[CAP];
    int b = blockIdx.x;
    int t = threadIdx.x;
    int base = b * CAP;
    int cnt = min(gcursor[b], CAP);

    if (t < 128) ldeg[t] = 0;
    __syncthreads();
    for (int i = t; i < cnt; i += 256)
        atomicAdd(&ldeg[bucket_buf[base + i] & 127], 1);
    __syncthreads();

    if (t < 128) lexc[t] = ldeg[t];
    __syncthreads();
    for (int off = 1; off < 128; off <<= 1) {
        int v = (t >= off && t < 128) ? lexc[t - off] : 0;
        __syncthreads();
        if (t < 128) lexc[t] += v;
        __syncthreads();
    }
    if (t < 128) {
        int ex = lexc[t] - ldeg[t];
        lcur2[t] = ex;
        int node = (b << 7) + t;
        if (node < N) {
            row_start[node] = base + ex;
            degA[node] = ldeg[t];
            dinv[node] = rsqrtf(fmaxf((float)ldeg[t], 1.0f));
        }
    }
    __syncthreads();

    for (int i = t; i < cnt; i += 256) {
        unsigned int v = bucket_buf[base + i];
        int pos = atomicAdd(&lcur2[(int)(v & 127)], 1);
        colLDS[pos] = (int)(v >> 7);
    }
    __syncthreads();
    for (int i = t; i < cnt; i += 256)
        bucket_buf[base + i] = (unsigned int)colLDS[i];   // now = col[]
}

// ---------------- MLP in via MFMA: h = relu(feat@W1+b1)@W2+b2 ----------------
__global__ __launch_bounds__(256) void mlp_kernel(const float* __restrict__ feat,
                                                  const float* __restrict__ W1,
                                                  const float* __restrict__ b1,
                                                  const float* __restrict__ W2,
                                                  const float* __restrict__ b2,
                                                  const float* __restrict__ dinv,
                                                  float* __restrict__ hout,
                                                  uint4* __restrict__ hs_b, int N) {
    __shared__ unsigned short w1t[32][72];      // W1^T [j][k], pad 64->72
    __shared__ unsigned short w2t[32][40];      // W2^T [j][k], pad 32->40
    __shared__ unsigned short h1t[4][16][40];   // per-wave relu(h1) [row][j] bf16
    __shared__ unsigned short h2t[4][16][40];   // per-wave dinv*h2   [row][j] bf16

    int lt = threadIdx.x;
    for (int i = lt; i < FIN * HD; i += 256) {
        int k = i >> 5, j = i & 31;
        w1t[j][k] = (unsigned short)f2bf(W1[i]);
    }
    for (int i = lt; i < HD * HD; i += 256) {
        int k = i >> 5, j = i & 31;
        w2t[j][k] = (unsigned short)f2bf(W2[i]);
    }
    __syncthreads();

    int w = lt >> 6;
    int l = lt & 63;
    int g = l >> 4;
    int c = l & 15;
    int base = blockIdx.x * 64 + w * 16;

    int row = base + c;
    int rowc = (row < N) ? row : (N - 1);
    const float* fr = feat + (size_t)rowc * FIN;
    bf16x8 a1[2];
#pragma unroll
    for (int ks = 0; ks < 2; ++ks) {
        const float4* p = (const float4*)(fr + ks * 32 + 8 * g);
        float4 u0 = p[0], u1 = p[1];
        bf16x8 a;
        a[0] = (short)f2bf(u0.x); a[1] = (short)f2bf(u0.y);
        a[2] = (short)f2bf(u0.z); a[3] = (short)f2bf(u0.w);
        a[4] = (short)f2bf(u1.x); a[5] = (short)f2bf(u1.y);
        a[6] = (short)f2bf(u1.z); a[7] = (short)f2bf(u1.w);
        a1[ks] = a;
    }

    f32x4 acc[2];
#pragma unroll
    for (int nt = 0; nt < 2; ++nt) { acc[nt][0] = 0.f; acc[nt][1] = 0.f; acc[nt][2] = 0.f; acc[nt][3] = 0.f; }
#pragma unroll
    for (int nt = 0; nt < 2; ++nt) {
#pragma unroll
        for (int ks = 0; ks < 2; ++ks) {
            bf16x8 b = *(const bf16x8*)&w1t[nt * 16 + c][ks * 32 + 8 * g];
            acc[nt] = __builtin_amdgcn_mfma_f32_16x16x32_bf16(a1[ks], b, acc[nt], 0, 0, 0);
        }
    }

    float b1v0 = b1[c], b1v1 = b1[16 + c];
#pragma unroll
    for (int r = 0; r < 4; ++r) {
        h1t[w][4 * g + r][c]      = (unsigned short)f2bf(fmaxf(acc[0][r] + b1v0, 0.0f));
        h1t[w][4 * g + r][16 + c] = (unsigned short)f2bf(fmaxf(acc[1][r] + b1v1, 0.0f));
    }
    __syncthreads();

    bf16x8 a2 = *(const bf16x8*)&h1t[w][c][8 * g];
    f32x4 acc2[2];
#pragma unroll
    for (int nt = 0; nt < 2; ++nt) { acc2[nt][0] = 0.f; acc2[nt][1] = 0.f; acc2[nt][2] = 0.f; acc2[nt][3] = 0.f; }
#pragma unroll
    for (int nt = 0; nt < 2; ++nt) {
        bf16x8 b = *(const bf16x8*)&w2t[nt * 16 + c][8 * g];
        acc2[nt] = __builtin_amdgcn_mfma_f32_16x16x32_bf16(a2, b, acc2[nt], 0, 0, 0);
    }

    float b2v0 = b2[c], b2v1 = b2[16 + c];
#pragma unroll
    for (int r = 0; r < 4; ++r) {
        int rr = base + 4 * g + r;
        int rc = (rr < N) ? rr : (N - 1);
        float dv = dinv[rc];
        float v0 = acc2[0][r] + b2v0;
        float v1 = acc2[1][r] + b2v1;
        if (rr < N) {
            hout[(size_t)rr * HD + c]      = v0;
            hout[(size_t)rr * HD + 16 + c] = v1;
        }
        h2t[w][4 * g + r][c]      = (unsigned short)f2bf(dv * v0);
        h2t[w][4 * g + r][16 + c] = (unsigned short)f2bf(dv * v1);
    }
    __syncthreads();

    int nrow = base + c;
    if (nrow < N) {
        uint4 u = *(const uint4*)&h2t[w][c][8 * g];
        hs_b[(size_t)nrow * 4 + g] = u;
    }
}

// ---------------- gather #1: acc = sum hs[col];
//                  f1s_b = bf16(dinv[n]*(h[n] + dinv[n]*acc)) ----------------
// 4 lanes/node (quad = one merged 64B line request).
// Unroll x8 leading batch: 8 independent col->table chains per thread in
// flight (R11 counters: no pipe saturated -> latency x concurrency bound;
// this doubles outstanding line requests at fixed occupancy).
__global__ __launch_bounds__(256) void gather1_kernel(const float* __restrict__ h,
                                                      const uint4* __restrict__ hs_b,
                                                      const float* __restrict__ dinv,
                                                      const int* __restrict__ row_start,
                                                      const int* __restrict__ deg,
                                                      const int* __restrict__ col,
                                                      uint4* __restrict__ f1s_b, int N) {
    int t = blockIdx.x * 256 + threadIdx.x;
    int n = t >> 2;
    if (n >= N) return;
    int q = t & 3;
    int s = row_start[n];
    int e_end = s + deg[n];
    float acc[8] = {0.f, 0.f, 0.f, 0.f, 0.f, 0.f, 0.f, 0.f};
    int e = s;
    for (; e + 8 <= e_end; e += 8) {
        int cc[8];
#pragma unroll
        for (int u = 0; u < 8; ++u) cc[u] = col[e + u];
        uint4 v[8];
#pragma unroll
        for (int u = 0; u < 8; ++u) v[u] = hs_b[(size_t)cc[u] * 4 + q];
#pragma unroll
        for (int u = 0; u < 8; ++u) {
            acc[0] += bflo(v[u].x); acc[1] += bfhi(v[u].x);
            acc[2] += bflo(v[u].y); acc[3] += bfhi(v[u].y);
            acc[4] += bflo(v[u].z); acc[5] += bfhi(v[u].z);
            acc[6] += bflo(v[u].w); acc[7] += bfhi(v[u].w);
        }
    }
    for (; e + 4 <= e_end; e += 4) {
        int c0 = col[e], c1 = col[e + 1], c2 = col[e + 2], c3 = col[e + 3];
        uint4 v0 = hs_b[(size_t)c0 * 4 + q];
        uint4 v1 = hs_b[(size_t)c1 * 4 + q];
        uint4 v2 = hs_b[(size_t)c2 * 4 + q];
        uint4 v3 = hs_b[(size_t)c3 * 4 + q];
        acc[0] += (bflo(v0.x) + bflo(v1.x)) + (bflo(v2.x) + bflo(v3.x));
        acc[1] += (bfhi(v0.x) + bfhi(v1.x)) + (bfhi(v2.x) + bfhi(v3.x));
        acc[2] += (bflo(v0.y) + bflo(v1.y)) + (bflo(v2.y) + bflo(v3.y));
        acc[3] += (bfhi(v0.y) + bfhi(v1.y)) + (bfhi(v2.y) + bfhi(v3.y));
        acc[4] += (bflo(v0.z) + bflo(v1.z)) + (bflo(v2.z) + bflo(v3.z));
        acc[5] += (bfhi(v0.z) + bfhi(v1.z)) + (bfhi(v2.z) + bfhi(v3.z));
        acc[6] += (bflo(v0.w) + bflo(v1.w)) + (bflo(v2.w) + bflo(v3.w));
        acc[7] += (bfhi(v0.w) + bfhi(v1.w)) + (bfhi(v2.w) + bfhi(v3.w));
    }
    for (; e < e_end; ++e) {
        int c = col[e];
        uint4 v = hs_b[(size_t)c * 4 + q];
        acc[0] += bflo(v.x); acc[1] += bfhi(v.x);
        acc[2] += bflo(v.y); acc[3] += bfhi(v.y);
        acc[4] += bflo(v.z); acc[5] += bfhi(v.z);
        acc[6] += bflo(v.w); acc[7] += bfhi(v.w);
    }
    float di = dinv[n];
    const float4* h4 = (const float4*)h;
    float4 ha = h4[(size_t)n * 8 + 2 * q];
    float4 hb = h4[(size_t)n * 8 + 2 * q + 1];
    float f[8] = {fmaf(di, acc[0], ha.x), fmaf(di, acc[1], ha.y),
                  fmaf(di, acc[2], ha.z), fmaf(di, acc[3], ha.w),
                  fmaf(di, acc[4], hb.x), fmaf(di, acc[5], hb.y),
                  fmaf(di, acc[6], hb.z), fmaf(di, acc[7], hb.w)};
    uint4 u;
    u.x = pack2(di * f[0], di * f[1]);
    u.y = pack2(di * f[2], di * f[3]);
    u.z = pack2(di * f[4], di * f[5]);
    u.w = pack2(di * f[6], di * f[7]);
    f1s_b[(size_t)n * 4 + q] = u;
}

// ---------------- fused gather #2 + MFMA epilogue ----------------
// Identity: p_i = y_i@W2 + b2 with y_i = al_i*h + be_i*a + ga_i*b (a=d*s0, b=d*t1);
// res = (sum_i score_i*y_i)@Wc. A = W2^T (LDS), B = per-node data fragments.
// hi/lo bf16 split on BOTH operands (3 MFMAs/product) = fp32-equivalent.
// av is RECOVERED from the node's own f1s_b row (av = f1s/di - h);
// t1 gather unrolled x8 (independent chains) like gather1.
__global__ __launch_bounds__(256) void final_kernel(const float* __restrict__ h,
                                                    const uint4* __restrict__ f1s_b,
                                                    const float* __restrict__ dinv,
                                                    const int* __restrict__ row_start,
                                                    const int* __restrict__ deg,
                                                    const int* __restrict__ col,
                                                    const float* __restrict__ W2,
                                                    const float* __restrict__ b2,
                                                    const float* __restrict__ Wc,
                                                    const float* __restrict__ bc,
                                                    const float* __restrict__ wbern,
                                                    float* __restrict__ out, int N) {
    __shared__ unsigned short w2h[32][40];   // bf16 hi of W2^T [j][k]
    __shared__ unsigned short w2l[32][40];   // bf16 lo (residual)

    int lt = threadIdx.x;
    for (int i = lt; i < HD * HD; i += 256) {
        int k = i >> 5, j = i & 31;
        float x = W2[i];
        unsigned int uh = f2bf(x);
        float xh = __uint_as_float(uh << 16);
        w2h[j][k] = (unsigned short)uh;
        w2l[j][k] = (unsigned short)f2bf(x - xh);
    }
    __syncthreads();

    int w = lt >> 6;
    int l = lt & 63;
    int g = l >> 4;             // k-block owner
    int c = l & 15;             // node within wave tile / A-row j
    int node = blockIdx.x * 64 + w * 16 + c;
    int nc = (node < N) ? node : (N - 1);
    int kb = 8 * g;

    // ---- gather t1 for (node, k-block): 8 chains in flight ----
    int s = row_start[nc];
    int e_end = s + deg[nc];
    float acc[8] = {0.f, 0.f, 0.f, 0.f, 0.f, 0.f, 0.f, 0.f};
    int e = s;
    for (; e + 8 <= e_end; e += 8) {
        int cc[8];
#pragma unroll
        for (int u = 0; u < 8; ++u) cc[u] = col[e + u];
        uint4 v[8];
#pragma unroll
        for (int u = 0; u < 8; ++u) v[u] = f1s_b[(size_t)cc[u] * 4 + g];
#pragma unroll
        for (int u = 0; u < 8; ++u) {
            acc[0] += bflo(v[u].x); acc[1] += bfhi(v[u].x);
            acc[2] += bflo(v[u].y); acc[3] += bfhi(v[u].y);
            acc[4] += bflo(v[u].z); acc[5] += bfhi(v[u].z);
            acc[6] += bflo(v[u].w); acc[7] += bfhi(v[u].w);
        }
    }
    for (; e + 4 <= e_end; e += 4) {
        int c0 = col[e], c1 = col[e + 1], c2 = col[e + 2], c3 = col[e + 3];
        uint4 v0 = f1s_b[(size_t)c0 * 4 + g];
        uint4 v1 = f1s_b[(size_t)c1 * 4 + g];
        uint4 v2 = f1s_b[(size_t)c2 * 4 + g];
        uint4 v3 = f1s_b[(size_t)c3 * 4 + g];
        acc[0] += (bflo(v0.x) + bflo(v1.x)) + (bflo(v2.x) + bflo(v3.x));
        acc[1] += (bfhi(v0.x) + bfhi(v1.x)) + (bfhi(v2.x) + bfhi(v3.x));
        acc[2] += (bflo(v0.y) + bflo(v1.y)) + (bflo(v2.y) + bflo(v3.y));
        acc[3] += (bfhi(v0.y) + bfhi(v1.y)) + (bfhi(v2.y) + bfhi(v3.y));
        acc[4] += (bflo(v0.z) + bflo(v1.z)) + (bflo(v2.z) + bflo(v3.z));
        acc[5] += (bfhi(v0.z) + bfhi(v1.z)) + (bfhi(v2.z) + bfhi(v3.z));
        acc[6] += (bflo(v0.w) + bflo(v1.w)) + (bflo(v2.w) + bflo(v3.w));
        acc[7] += (bfhi(v0.w) + bfhi(v1.w)) + (bfhi(v2.w) + bfhi(v3.w));
    }
    for (; e < e_end; ++e) {
        int cc = col[e];
        uint4 v = f1s_b[(size_t)cc * 4 + g];
        acc[0] += bflo(v.x); acc[1] += bfhi(v.x);
        acc[2] += bflo(v.y); acc[3] += bfhi(v.y);
        acc[4] += bflo(v.z); acc[5] += bfhi(v.z);
        acc[6] += bflo(v.w); acc[7] += bfhi(v.w);
    }

    float di = dinv[nc];
    float rdi = 1.0f / di;
    const float4* hp = (const float4*)(h + (size_t)nc * HD + kb);
    float4 h0 = hp[0], h1v = hp[1];
    float hv[8] = {h0.x, h0.y, h0.z, h0.w, h1v.x, h1v.y, h1v.z, h1v.w};

    // own f1s row -> av recovery (likely L2-hot: same table the gather pulls)
    uint4 fv = f1s_b[(size_t)nc * 4 + g];
    float fl[8] = {bflo(fv.x), bfhi(fv.x), bflo(fv.y), bfhi(fv.y),
                   bflo(fv.z), bfhi(fv.z), bflo(fv.w), bfhi(fv.w)};
    float av[8];
#pragma unroll
    for (int k = 0; k < 8; ++k) av[k] = fmaf(fl[k], rdi, -hv[k]);

    float bv[8];
#pragma unroll
    for (int k = 0; k < 8; ++k) bv[k] = di * acc[k];

    // ---- Bern coefficients (uniform over nodes) ----
    float al[NL], be[NL], ga[NL];
#pragma unroll
    for (int i = 0; i < NL; ++i) {
        float wa = 0.25f * fmaxf(wbern[i * 3 + 0], 0.0f);
        float wb = 0.50f * fmaxf(wbern[i * 3 + 1], 0.0f);
        float wc = 0.25f * fmaxf(wbern[i * 3 + 2], 0.0f);
        al[i] = wa + wb + wc;          // coeff of h
        be[i] = wa + wb - 3.0f * wc;   // coeff of a
        ga[i] = wa - wb + wc;          // coeff of b
    }

    // ---- y_i fp32 (kept for the exact z->Wc path) ----
    float y0[8], y1[8], y2[8];
#pragma unroll
    for (int k = 0; k < 8; ++k) {
        y0[k] = fmaf(ga[0], bv[k], fmaf(be[0], av[k], al[0] * hv[k]));
        y1[k] = fmaf(ga[1], bv[k], fmaf(be[1], av[k], al[1] * hv[k]));
        y2[k] = fmaf(ga[2], bv[k], fmaf(be[2], av[k], al[2] * hv[k]));
    }

    // ---- B fragments (data): hi/lo pairs for h, y0, y1, y2 ----
    bf16x8 fbh[4], fbl[4];
    pack_hilo(hv, fbh[0], fbl[0]);
    pack_hilo(y0, fbh[1], fbl[1]);
    pack_hilo(y1, fbh[2], fbl[2]);
    pack_hilo(y2, fbh[3], fbl[3]);

    // ---- MFMA: D[m][jt] = W2^T(jt-tile) @ data_m ; 3 products per pair ----
    f32x4 D[4][2];
#pragma unroll
    for (int m = 0; m < 4; ++m)
#pragma unroll
        for (int jt = 0; jt < 2; ++jt) { D[m][jt][0] = 0.f; D[m][jt][1] = 0.f; D[m][jt][2] = 0.f; D[m][jt][3] = 0.f; }
#pragma unroll
    for (int jt = 0; jt < 2; ++jt) {
        bf16x8 ah = *(const bf16x8*)&w2h[jt * 16 + c][kb];
        bf16x8 alo = *(const bf16x8*)&w2l[jt * 16 + c][kb];
#pragma unroll
        for (int m = 0; m < 4; ++m) {
            D[m][jt] = __builtin_amdgcn_mfma_f32_16x16x32_bf16(ah,  fbh[m], D[m][jt], 0, 0, 0);
            D[m][jt] = __builtin_amdgcn_mfma_f32_16x16x32_bf16(alo, fbh[m], D[m][jt], 0, 0, 0);
            D[m][jt] = __builtin_amdgcn_mfma_f32_16x16x32_bf16(ah,  fbl[m], D[m][jt], 0, 0, 0);
        }
    }

    // ---- bias + tanh; logit partials: lane holds j = jt*16 + 4g + r, node c ----
    float4 b2lo = ((const float4*)b2)[g];
    float4 b2hi = ((const float4*)b2)[4 + g];
    float b2j[2][4] = {{b2lo.x, b2lo.y, b2lo.z, b2lo.w}, {b2hi.x, b2hi.y, b2hi.z, b2hi.w}};
    float lg[NL] = {0.f, 0.f, 0.f};
#pragma unroll
    for (int jt = 0; jt < 2; ++jt) {
#pragma unroll
        for (int r = 0; r < 4; ++r) {
            float xp = fast_tanh(D[0][jt][r] + b2j[jt][r]);
            lg[0] = fmaf(fast_tanh(D[1][jt][r] + b2j[jt][r]), xp, lg[0]);
            lg[1] = fmaf(fast_tanh(D[2][jt][r] + b2j[jt][r]), xp, lg[1]);
            lg[2] = fmaf(fast_tanh(D[3][jt][r] + b2j[jt][r]), xp, lg[2]);
        }
    }
#pragma unroll
    for (int i = 0; i < NL; ++i) {
        lg[i] += __shfl_xor(lg[i], 16);
        lg[i] += __shfl_xor(lg[i], 32);
    }

    // ---- softmax over 3 filters (redundant across g: fine) ----
    float m = fmaxf(lg[0], fmaxf(lg[1], lg[2]));
    float e0 = __expf(lg[0] - m), e1 = __expf(lg[1] - m), e2 = __expf(lg[2] - m);
    float inv = 1.0f / (e0 + e1 + e2);
    float s0c = e0 * inv, s1c = e1 * inv, s2c = e2 * inv;

    // ---- z = sum_i score_i * y_i (fp32), out = bc + z@Wc (reduce over g) ----
    float o0 = 0.f, o1 = 0.f;
    const float2* wcp = (const float2*)Wc;
#pragma unroll
    for (int k = 0; k < 8; ++k) {
        float z = fmaf(s2c, y2[k], fmaf(s1c, y1[k], s0c * y0[k]));
        float2 wck = wcp[kb + k];
        o0 = fmaf(z, wck.x, o0);
        o1 = fmaf(z, wck.y, o1);
    }
    o0 += __shfl_xor(o0, 16); o0 += __shfl_xor(o0, 32);
    o1 += __shfl_xor(o1, 16); o1 += __shfl_xor(o1, 32);

    if (g == 0 && node < N) {
        float2 o = {bc[0] + o0, bc[1] + o1};
        ((float2*)out)[node] = o;
    }
}

extern "C" void kernel_launch(void* const* d_in, const int* in_sizes, int n_in,
                              void* d_out, int out_size, void* d_ws, size_t ws_size,
                              hipStream_t stream) {
    const float* feature = (const float*)d_in[0];
    const float* W1 = (const float*)d_in[1];
    const float* b1 = (const float*)d_in[2];
    const float* W2 = (const float*)d_in[3];
    const float* b2 = (const float*)d_in[4];
    const float* Wc = (const float*)d_in[5];
    const float* bc = (const float*)d_in[6];
    const float* wbern = (const float*)d_in[7];
    const int* src = (const int*)d_in[8];
    const int* dst = (const int*)d_in[9];

    const int N = in_sizes[0] / FIN;   // 100000
    const int E = in_sizes[8];         // 1600000
    const int B = (N + 127) >> 7;      // 782 buckets

    // workspace layout
    char* p = (char*)d_ws;
    size_t Np = ((size_t)N + 255) & ~(size_t)255;
    size_t N32 = (size_t)N * HD;
    int* gcursor   = (int*)p;              p += ((size_t)BMAX) * 4;
    int* row_start = (int*)p;              p += Np * 4;
    int* degA      = (int*)p;              p += Np * 4;
    float* dinv    = (float*)p;            p += Np * 4;
    unsigned int* bucket_buf = (unsigned int*)p;  p += (size_t)B * CAP * 4;  // becomes col[]
    float* h    = (float*)p;               p += N32 * 4;
    uint4* hs_b = (uint4*)p;               p += N32 * 2;   // bf16, 64B/row
    uint4* f1s_b= (uint4*)p;               p += N32 * 2;

    int bG = ((N * 4) + 255) / 256;        // 4 lanes per node
    int bM = (N + 63) / 64;                // 64 nodes per block (4 waves x 16)
    int nTiles = (E + TILE - 1) / TILE;

    hipMemsetAsync(gcursor, 0, (size_t)BMAX * 4, stream);
    partition_kernel<<<nTiles, 256, 0, stream>>>(src, dst, gcursor, bucket_buf, E);
    bucket_csr_kernel<<<B, 256, 0, stream>>>(bucket_buf, gcursor, row_start, degA, dinv, N);

    mlp_kernel<<<bM, 256, 0, stream>>>(feature, W1, b1, W2, b2, dinv, h, hs_b, N);

    const int* col = (const int*)bucket_buf;
    gather1_kernel<<<bG, 256, 0, stream>>>(h, hs_b, dinv, row_start, degA, col, f1s_b, N);

    final_kernel<<<bM, 256, 0, stream>>>(h, f1s_b, dinv, row_start, degA, col,
                                         W2, b2, Wc, bc, wbern, (float*)d_out, N);
}